// Round 7
// baseline (211.482 us; speedup 1.0000x reference)
//
#include <hip/hip_runtime.h>
#include <stdint.h>

#define DIM   128
#define NK    512
#define SPB   32768
#define NBLK  1024

#define E_OFF 16777216
#define D_OFF 83886080
#define L_OFF 150994944

typedef __attribute__((ext_vector_type(16))) float f32x16;
typedef __attribute__((ext_vector_type(4)))  float f32x4;
typedef __attribute__((ext_vector_type(8)))  short bf16x8;

__device__ __forceinline__ unsigned int rne_bf16(float f) {
    union { float f; unsigned int u; } v; v.f = f;
    return (v.u + 0x7FFFu + ((v.u >> 16) & 1u)) >> 16;
}
__device__ __forceinline__ float bf16f(unsigned int h) {
    union { float f; unsigned int u; } v; v.u = h << 16;
    return v.f;
}
__device__ __forceinline__ unsigned int f2u(float f) {
    union { float f; unsigned int u; } v; v.f = f; return v.u;
}
__device__ __forceinline__ float u2f(unsigned int u) {
    union { float f; unsigned int u; } v; v.u = u; return v.f;
}

// Pre-kernel: codebook row sq-norms + 2-way bf16 split in MFMA-fragment-major
// layout: index ((c*8+t)*64 + lane), 8 bf16/lane = cb[c*32+(l&31)][t*16+(l>>5)*8+j]
__global__ __launch_bounds__(256) void prep_kernel(
        const float* __restrict__ cb, float* __restrict__ ww,
        short* __restrict__ cbh, short* __restrict__ cbm) {
    const int tid = blockIdx.x * 256 + threadIdx.x;   // 0..8191
    if (tid < NK) {
        const float* row = cb + tid * DIM;
        float s = 0.f;
        #pragma unroll 8
        for (int d = 0; d < DIM; ++d) s = fmaf(row[d], row[d], s);
        ww[tid] = s;
    }
    const int l = tid & 63;
    const int t = (tid >> 6) & 7;
    const int c = tid >> 9;
    const float* src = cb + (c * 32 + (l & 31)) * DIM + t * 16 + ((l >> 5) << 3);
    bf16x8 vh, vm;
    #pragma unroll
    for (int j = 0; j < 8; ++j) {
        float f = src[j];
        unsigned int hu = rne_bf16(f);
        unsigned int mu = rne_bf16(f - bf16f(hu));
        vh[j] = (short)hu; vm[j] = (short)mu;
    }
    ((bf16x8*)cbh)[tid] = vh;
    ((bf16x8*)cbm)[tid] = vm;
}

__global__ __launch_bounds__(256, 3) void vq_main(
        const float* __restrict__ x, const float* __restrict__ cb,
        const float* __restrict__ ww,
        const short* __restrict__ cbh, const short* __restrict__ cbm,
        float* __restrict__ out, float* __restrict__ partials) {
    __shared__ float xx_s[128];
    __shared__ int   idx_s[128];
    __shared__ float red_s[128];

    const int tid  = threadIdx.x;
    const int bid  = blockIdx.x;
    const int lane = tid & 63;
    const int w    = tid >> 6;
    const int bb   = bid >> 8;            // batch index (256 blocks per batch elem)
    const int s0   = (bid & 255) << 7;    // spatial base
    const int hi4  = (lane >> 5) << 2;
    const int rloc = (w << 5) + (lane & 31);   // this lane's x row (0..127)
    const int kb   = (lane >> 5) << 3;         // k-offset 0 or 8

    const float* xrow = x + (size_t)bb * (DIM * SPB) + s0 + rloc;

    // ---- phase 1: direct global fragment loads (nt) + 2-way split + local norm
    bf16x8 ah[8], am[8];
    float xxl = 0.f;
    #pragma unroll
    for (int t = 0; t < 8; ++t) {
        bf16x8 vh, vm;
        #pragma unroll
        for (int j = 0; j < 8; ++j) {
            float f = __builtin_nontemporal_load(xrow + (size_t)(t * 16 + kb + j) * SPB);
            xxl = fmaf(f, f, xxl);
            unsigned int hu = rne_bf16(f);
            unsigned int mu = rne_bf16(f - bf16f(hu));
            vh[j] = (short)hu; vm[j] = (short)mu;
        }
        ah[t] = vh; am[t] = vm;
    }
    // full row norm: lane and lane^32 share a row, complementary k-halves
    xxl += __shfl_xor(xxl, 32, 64);
    if (lane < 32) xx_s[rloc] = xxl;
    __syncthreads();

    float xxr[16];
    #pragma unroll
    for (int r = 0; r < 16; ++r)
        xxr[r] = xx_s[(w << 5) + (r & 3) + ((r >> 2) << 3) + hi4];

    unsigned int best[16];
    #pragma unroll
    for (int r = 0; r < 16; ++r) best[r] = 0xFFFFFFFFu;

    const int col = lane & 31;
    const int rowbase = bid * 128 + (w << 5);

    // ---- main loop: 16 col-tiles of 32 codes; 3-term split MFMA; no barriers
    // dist stores are PLAIN (L2 write-back coalesces the scattered temporal order)
    for (int c = 0; c < 16; ++c) {
        f32x16 acc0 = {};
        f32x16 acc1 = {};
        const bf16x8* ph = (const bf16x8*)cbh + c * 512 + lane;
        const bf16x8* pm = (const bf16x8*)cbm + c * 512 + lane;
        #pragma unroll
        for (int t = 0; t < 8; ++t) {
            bf16x8 bh = ph[t * 64];
            bf16x8 bm = pm[t * 64];
            acc0 = __builtin_amdgcn_mfma_f32_32x32x16_bf16(ah[t], bh, acc0, 0, 0, 0);
            acc1 = __builtin_amdgcn_mfma_f32_32x32x16_bf16(ah[t], bm, acc1, 0, 0, 0);
            acc0 = __builtin_amdgcn_mfma_f32_32x32x16_bf16(am[t], bh, acc0, 0, 0, 0);
        }
        const int kcol = (c << 5) + col;
        const float wwc = ww[kcol];
        #pragma unroll
        for (int r = 0; r < 16; ++r) {
            float dot  = acc0[r] + acc1[r];
            float dist = fmaf(-2.f, dot, xxr[r] + wwc);
            int rl = (r & 3) + ((r >> 2) << 3) + hi4;
            out[(size_t)D_OFF + (size_t)(rowbase + rl) * NK + kcol] = dist;
            unsigned int pack = (f2u(dist) & ~511u) | (unsigned int)kcol;
            best[r] = pack < best[r] ? pack : best[r];
        }
    }

    // ---- argmin: u32 shuffle-min over the 32-lane column group
    #pragma unroll
    for (int r = 0; r < 16; ++r) {
        unsigned int b = best[r];
        #pragma unroll
        for (int m = 16; m >= 1; m >>= 1) {
            unsigned int ob = __shfl_xor(b, m, 64);
            b = ob < b ? ob : b;
        }
        best[r] = b;
    }
    if ((lane & 31) == 0) {
        #pragma unroll
        for (int r = 0; r < 16; ++r) {
            int row = (w << 5) + (r & 3) + ((r >> 2) << 3) + hi4;
            idx_s[row] = (int)(best[r] & 511u);
            red_s[row] = u2f(best[r] & ~511u);
        }
    }
    __syncthreads();

    // ---- loss partial (wave 0) — deterministic shuffle sum
    if (tid < 64) {
        float s = red_s[tid] + red_s[tid + 64];
        #pragma unroll
        for (int m = 32; m >= 1; m >>= 1) s += __shfl_xor(s, m, 64);
        if (tid == 0) partials[bid] = s;
    }

    // ---- quantized: gather cb row to regs, PLAIN scalar column stores
    {
        int r = tid >> 1, h = tid & 1;
        const float* src = cb + (size_t)idx_s[r] * DIM + h * 64;
        float* ob = out + (size_t)bb * (DIM * SPB) + s0 + r;
        #pragma unroll
        for (int q = 0; q < 16; ++q) {
            f32x4 v = *(const f32x4*)(src + (q << 2));
            #pragma unroll
            for (int e = 0; e < 4; ++e) {
                int d = h * 64 + (q << 2) + e;
                ob[(size_t)d * SPB] = v[e];
            }
        }
    }

    // ---- encoding one-hot: fused zero+one-hot, lane-contiguous f32x4 nt stores
    {
        float* ebase = out + (size_t)E_OFF + (size_t)bid * (128 * NK);
        #pragma unroll
        for (int j = 0; j < 64; ++j) {
            int v   = j * 256 + tid;       // f32x4 index within block's 128x512 region
            int r   = v >> 7;
            int cb4 = (v & 127) << 2;
            int idxr = idx_s[r];
            f32x4 val;
            val[0] = (idxr == cb4    ) ? 1.0f : 0.0f;
            val[1] = (idxr == cb4 + 1) ? 1.0f : 0.0f;
            val[2] = (idxr == cb4 + 2) ? 1.0f : 0.0f;
            val[3] = (idxr == cb4 + 3) ? 1.0f : 0.0f;
            __builtin_nontemporal_store(val, (f32x4*)ebase + v);
        }
    }
}

__global__ __launch_bounds__(256) void loss_kernel(const float* __restrict__ partials,
                                                   float* __restrict__ out) {
    __shared__ double sd[256];
    int tid = threadIdx.x;
    double s = 0.0;
    for (int i = tid; i < NBLK; i += 256) s += (double)partials[i];
    sd[tid] = s;
    __syncthreads();
    for (int k = 128; k > 0; k >>= 1) {
        if (tid < k) sd[tid] += sd[tid + k];
        __syncthreads();
    }
    if (tid == 0) out[L_OFF] = (float)(2.0 * sd[0] / 16777216.0);
}

extern "C" void kernel_launch(void* const* d_in, const int* in_sizes, int n_in,
                              void* d_out, int out_size, void* d_ws, size_t ws_size,
                              hipStream_t stream) {
    const float* x  = (const float*)d_in[0];
    const float* cb = (const float*)d_in[1];
    float* out = (float*)d_out;
    char*  ws  = (char*)d_ws;
    float* ww  = (float*)ws;                          // 2048 B
    short* cbh = (short*)(ws + 2048);                 // 131072 B
    short* cbm = (short*)(ws + 2048 + 131072);        // 131072 B
    float* partials = (float*)(ws + 2048 + 262144);   // 4096 B

    prep_kernel<<<32, 256, 0, stream>>>(cb, ww, cbh, cbm);
    vq_main<<<NBLK, 256, 0, stream>>>(x, cb, ww, cbh, cbm, out, partials);
    loss_kernel<<<1, 256, 0, stream>>>(partials, out);
}

// Round 8
// 197.617 us; speedup vs baseline: 1.0702x; 1.0702x over previous
//
#include <hip/hip_runtime.h>
#include <stdint.h>

#define DIM   128
#define NK    512
#define SPB   32768
#define NBLK  4096

#define E_OFF 16777216
#define D_OFF 83886080
#define L_OFF 150994944

typedef __attribute__((ext_vector_type(16))) float f32x16;
typedef __attribute__((ext_vector_type(4)))  float f32x4;
typedef __attribute__((ext_vector_type(8)))  short bf16x8;

__device__ __forceinline__ unsigned int rne_bf16(float f) {
    union { float f; unsigned int u; } v; v.f = f;
    return (v.u + 0x7FFFu + ((v.u >> 16) & 1u)) >> 16;
}
__device__ __forceinline__ float bf16f(unsigned int h) {
    union { float f; unsigned int u; } v; v.u = h << 16;
    return v.f;
}
__device__ __forceinline__ unsigned int f2u(float f) {
    union { float f; unsigned int u; } v; v.f = f; return v.u;
}
__device__ __forceinline__ float u2f(unsigned int u) {
    union { float f; unsigned int u; } v; v.u = u; return v.f;
}

// Pre-kernel: codebook row sq-norms + 2-way bf16 split in MFMA-fragment-major
// layout: index ((c*8+t)*64 + lane), 8 bf16/lane = cb[c*32+(l&31)][t*16+(l>>5)*8+j]
__global__ __launch_bounds__(256) void prep_kernel(
        const float* __restrict__ cb, float* __restrict__ ww,
        short* __restrict__ cbh, short* __restrict__ cbm) {
    const int tid = blockIdx.x * 256 + threadIdx.x;   // 0..8191
    if (tid < NK) {
        const float* row = cb + tid * DIM;
        float s = 0.f;
        #pragma unroll 8
        for (int d = 0; d < DIM; ++d) s = fmaf(row[d], row[d], s);
        ww[tid] = s;
    }
    const int l = tid & 63;
    const int t = (tid >> 6) & 7;
    const int c = tid >> 9;
    const float* src = cb + (c * 32 + (l & 31)) * DIM + t * 16 + ((l >> 5) << 3);
    bf16x8 vh, vm;
    #pragma unroll
    for (int j = 0; j < 8; ++j) {
        float f = src[j];
        unsigned int hu = rne_bf16(f);
        unsigned int mu = rne_bf16(f - bf16f(hu));
        vh[j] = (short)hu; vm[j] = (short)mu;
    }
    ((bf16x8*)cbh)[tid] = vh;
    ((bf16x8*)cbm)[tid] = vm;
}

// Block = 32 rows x 512 cols. Wave w computes col-tiles [4w,4w+4), staging dist
// into its private LDS column stripe (no barriers in the c-loop). One barrier,
// then the block streams 32 complete 2KB dist rows (page-dense), block-local
// argmin, enc (64KB contiguous), quant.
__global__ __launch_bounds__(256, 2) void vq_main(
        const float* __restrict__ x, const float* __restrict__ cb,
        const float* __restrict__ ww,
        const short* __restrict__ cbh, const short* __restrict__ cbm,
        float* __restrict__ out, float* __restrict__ partials) {
    __shared__ float        stage[32 * 512];   // 64KB dist tile [row][col]
    __shared__ unsigned int best_s[4 * 32];
    __shared__ int          idx_s[32];
    __shared__ float        red_s[32];

    const int tid   = threadIdx.x;
    const int bid   = blockIdx.x;
    const int lane  = tid & 63;
    const int w     = tid >> 6;
    const int bb    = bid >> 10;            // 1024 blocks per batch elem
    const int srel  = (bid & 1023) << 5;    // spatial base within batch
    const int hi4   = (lane >> 5) << 2;
    const int row32 = lane & 31;            // this lane's x row (0..31)
    const int kb    = (lane >> 5) << 3;     // k-offset 0 or 8

    const float* xrow = x + (size_t)bb * (DIM * SPB) + srel + row32;

    // ---- phase 1: direct global fragment loads (nt) + 2-way split + row norm
    // (all 4 waves load the same 16KB -> L1 hits; keeps phase barrier-free)
    bf16x8 ah[8], am[8];
    float xxl = 0.f;
    #pragma unroll
    for (int t = 0; t < 8; ++t) {
        bf16x8 vh, vm;
        #pragma unroll
        for (int j = 0; j < 8; ++j) {
            float f = __builtin_nontemporal_load(xrow + (size_t)(t * 16 + kb + j) * SPB);
            xxl = fmaf(f, f, xxl);
            unsigned int hu = rne_bf16(f);
            unsigned int mu = rne_bf16(f - bf16f(hu));
            vh[j] = (short)hu; vm[j] = (short)mu;
        }
        ah[t] = vh; am[t] = vm;
    }
    // lane & lane^32 hold complementary k-halves of the same row
    xxl += __shfl_xor(xxl, 32, 64);
    // xx for any row 0..31 lives at that lane index; bpermute-broadcast
    float xxr[16];
    #pragma unroll
    for (int r = 0; r < 16; ++r)
        xxr[r] = __shfl(xxl, (r & 3) + ((r >> 2) << 3) + hi4, 64);

    unsigned int best[16];
    #pragma unroll
    for (int r = 0; r < 16; ++r) best[r] = 0xFFFFFFFFu;

    // ---- main loop: 4 col-tiles per wave; stage to private LDS stripe
    #pragma unroll
    for (int i = 0; i < 4; ++i) {
        const int c = (w << 2) + i;
        f32x16 acc0 = {};
        f32x16 acc1 = {};
        const bf16x8* ph = (const bf16x8*)cbh + c * 512 + lane;
        const bf16x8* pm = (const bf16x8*)cbm + c * 512 + lane;
        #pragma unroll
        for (int t = 0; t < 8; ++t) {
            bf16x8 bh = ph[t * 64];
            bf16x8 bm = pm[t * 64];
            acc0 = __builtin_amdgcn_mfma_f32_32x32x16_bf16(ah[t], bh, acc0, 0, 0, 0);
            acc1 = __builtin_amdgcn_mfma_f32_32x32x16_bf16(ah[t], bm, acc1, 0, 0, 0);
            acc0 = __builtin_amdgcn_mfma_f32_32x32x16_bf16(am[t], bh, acc0, 0, 0, 0);
        }
        const int kcol = (c << 5) + row32;
        const float wwc = ww[kcol];
        #pragma unroll
        for (int r = 0; r < 16; ++r) {
            float dot  = acc0[r] + acc1[r];
            float dist = fmaf(-2.f, dot, xxr[r] + wwc);
            int rl = (r & 3) + ((r >> 2) << 3) + hi4;
            stage[rl * 512 + kcol] = dist;
            unsigned int pack = (f2u(dist) & ~511u) | (unsigned int)kcol;
            best[r] = pack < best[r] ? pack : best[r];
        }
    }

    // ---- wave-local argmin over the 32-lane column group
    #pragma unroll
    for (int r = 0; r < 16; ++r) {
        unsigned int b = best[r];
        #pragma unroll
        for (int m = 16; m >= 1; m >>= 1) {
            unsigned int ob = __shfl_xor(b, m, 64);
            b = ob < b ? ob : b;
        }
        best[r] = b;
    }
    if (row32 == 0) {   // lanes 0 and 32
        #pragma unroll
        for (int r = 0; r < 16; ++r)
            best_s[(w << 5) + (r & 3) + ((r >> 2) << 3) + hi4] = best[r];
    }
    __syncthreads();

    // ---- final argmin across the 4 waves (threads 0..31)
    if (tid < 32) {
        unsigned int pk = best_s[tid];
        #pragma unroll
        for (int ww2 = 1; ww2 < 4; ++ww2) {
            unsigned int o = best_s[(ww2 << 5) + tid];
            pk = o < pk ? o : pk;
        }
        idx_s[tid] = (int)(pk & 511u);
        red_s[tid] = u2f(pk & ~511u);
    }

    // ---- dist write-out: 16 rounds x 4KB fully-contiguous (page-dense)
    {
        f32x4* dbase = (f32x4*)(out + (size_t)D_OFF) + (size_t)bid * 4096;
        const f32x4* sbase = (const f32x4*)stage;
        #pragma unroll
        for (int k = 0; k < 16; ++k) {
            int flat4 = k * 256 + tid;
            __builtin_nontemporal_store(sbase[flat4], dbase + flat4);
        }
    }
    __syncthreads();

    // ---- loss partial (wave 0)
    if (tid < 64) {
        float s = (lane < 32) ? red_s[lane] : 0.f;
        #pragma unroll
        for (int m = 32; m >= 1; m >>= 1) s += __shfl_xor(s, m, 64);
        if (tid == 0) partials[bid] = s;
    }

    // ---- encoding one-hot: 64KB contiguous per block, fused zero+one-hot
    {
        f32x4* ebase = (f32x4*)(out + (size_t)E_OFF) + (size_t)bid * 4096;
        #pragma unroll
        for (int k = 0; k < 16; ++k) {
            int flat4 = k * 256 + tid;
            int r   = flat4 >> 7;
            int cb4 = (flat4 & 127) << 2;
            int idxr = idx_s[r];
            f32x4 val;
            val[0] = (idxr == cb4    ) ? 1.0f : 0.0f;
            val[1] = (idxr == cb4 + 1) ? 1.0f : 0.0f;
            val[2] = (idxr == cb4 + 2) ? 1.0f : 0.0f;
            val[3] = (idxr == cb4 + 3) ? 1.0f : 0.0f;
            __builtin_nontemporal_store(val, ebase + flat4);
        }
    }

    // ---- quantized: gather cb row (L1/L2-hot), scalar column stores (2x128B/inst)
    {
        int r  = tid & 31;          // spatial row
        int dg = tid >> 5;          // d-group 0..7 (16 d each)
        const float* src = cb + (size_t)idx_s[r] * DIM + (dg << 4);
        float* ob = out + (size_t)bb * (DIM * SPB) + srel + r;
        #pragma unroll
        for (int q = 0; q < 4; ++q) {
            f32x4 v = *(const f32x4*)(src + (q << 2));
            #pragma unroll
            for (int e = 0; e < 4; ++e) {
                int d = (dg << 4) + (q << 2) + e;
                __builtin_nontemporal_store(v[e], &ob[(size_t)d * SPB]);
            }
        }
    }
}

__global__ __launch_bounds__(256) void loss_kernel(const float* __restrict__ partials,
                                                   float* __restrict__ out) {
    __shared__ double sd[256];
    int tid = threadIdx.x;
    double s = 0.0;
    for (int i = tid; i < NBLK; i += 256) s += (double)partials[i];
    sd[tid] = s;
    __syncthreads();
    for (int k = 128; k > 0; k >>= 1) {
        if (tid < k) sd[tid] += sd[tid + k];
        __syncthreads();
    }
    if (tid == 0) out[L_OFF] = (float)(2.0 * sd[0] / 16777216.0);
}

extern "C" void kernel_launch(void* const* d_in, const int* in_sizes, int n_in,
                              void* d_out, int out_size, void* d_ws, size_t ws_size,
                              hipStream_t stream) {
    const float* x  = (const float*)d_in[0];
    const float* cb = (const float*)d_in[1];
    float* out = (float*)d_out;
    char*  ws  = (char*)d_ws;
    float* ww  = (float*)ws;                          // 2048 B
    short* cbh = (short*)(ws + 2048);                 // 131072 B
    short* cbm = (short*)(ws + 2048 + 131072);        // 131072 B
    float* partials = (float*)(ws + 2048 + 262144);   // 16384 B

    prep_kernel<<<32, 256, 0, stream>>>(cb, ww, cbh, cbm);
    vq_main<<<NBLK, 256, 0, stream>>>(x, cb, ww, cbh, cbm, out, partials);
    loss_kernel<<<1, 256, 0, stream>>>(partials, out);
}

// Round 9
// 177.489 us; speedup vs baseline: 1.1915x; 1.1134x over previous
//
#include <hip/hip_runtime.h>
#include <stdint.h>

#define DIM   128
#define NK    512
#define SPB   32768
#define NBLK  1024

#define E_OFF 16777216
#define D_OFF 83886080
#define L_OFF 150994944

typedef __attribute__((ext_vector_type(16))) float f32x16;
typedef __attribute__((ext_vector_type(4)))  float f32x4;
typedef __attribute__((ext_vector_type(8)))  short bf16x8;

__device__ __forceinline__ unsigned int rne_bf16(float f) {
    union { float f; unsigned int u; } v; v.f = f;
    return (v.u + 0x7FFFu + ((v.u >> 16) & 1u)) >> 16;
}
__device__ __forceinline__ float bf16f(unsigned int h) {
    union { float f; unsigned int u; } v; v.u = h << 16;
    return v.f;
}
__device__ __forceinline__ unsigned int f2u(float f) {
    union { float f; unsigned int u; } v; v.f = f; return v.u;
}
__device__ __forceinline__ float u2f(unsigned int u) {
    union { float f; unsigned int u; } v; v.u = u; return v.f;
}

// Pre-kernel: codebook row sq-norms + 2-way bf16 split in MFMA-fragment-major
// layout: index ((c*8+t)*64 + lane), 8 bf16/lane = cb[c*32+(l&31)][t*16+(l>>5)*8+j]
__global__ __launch_bounds__(256) void prep_kernel(
        const float* __restrict__ cb, float* __restrict__ ww,
        short* __restrict__ cbh, short* __restrict__ cbm) {
    const int tid = blockIdx.x * 256 + threadIdx.x;   // 0..8191
    if (tid < NK) {
        const float* row = cb + tid * DIM;
        float s = 0.f;
        #pragma unroll 8
        for (int d = 0; d < DIM; ++d) s = fmaf(row[d], row[d], s);
        ww[tid] = s;
    }
    const int l = tid & 63;
    const int t = (tid >> 6) & 7;
    const int c = tid >> 9;
    const float* src = cb + (c * 32 + (l & 31)) * DIM + t * 16 + ((l >> 5) << 3);
    bf16x8 vh, vm;
    #pragma unroll
    for (int j = 0; j < 8; ++j) {
        float f = src[j];
        unsigned int hu = rne_bf16(f);
        unsigned int mu = rne_bf16(f - bf16f(hu));
        vh[j] = (short)hu; vm[j] = (short)mu;
    }
    ((bf16x8*)cbh)[tid] = vh;
    ((bf16x8*)cbm)[tid] = vm;
}

__global__ __launch_bounds__(256, 3) void vq_main(
        const float* __restrict__ x, const float* __restrict__ cb,
        const float* __restrict__ ww,
        const short* __restrict__ cbh, const short* __restrict__ cbm,
        float* __restrict__ out, float* __restrict__ partials) {
    __shared__ float xx_s[128];
    __shared__ int   idx_s[128];
    __shared__ float red_s[128];

    const int tid  = threadIdx.x;
    const int bid  = blockIdx.x;
    const int lane = tid & 63;
    const int w    = tid >> 6;
    const int bb   = bid >> 8;            // batch index (256 blocks per batch elem)
    const int s0   = (bid & 255) << 7;    // spatial base
    const int hi4  = (lane >> 5) << 2;
    const int rloc = (w << 5) + (lane & 31);   // this lane's x row (0..127)
    const int kb   = (lane >> 5) << 3;         // k-offset 0 or 8

    const float* xrow = x + (size_t)bb * (DIM * SPB) + s0 + rloc;

    // ---- phase 1: direct global fragment loads (nt) + 2-way split + local norm
    bf16x8 ah[8], am[8];
    float xxl = 0.f;
    #pragma unroll
    for (int t = 0; t < 8; ++t) {
        bf16x8 vh, vm;
        #pragma unroll
        for (int j = 0; j < 8; ++j) {
            float f = __builtin_nontemporal_load(xrow + (size_t)(t * 16 + kb + j) * SPB);
            xxl = fmaf(f, f, xxl);
            unsigned int hu = rne_bf16(f);
            unsigned int mu = rne_bf16(f - bf16f(hu));
            vh[j] = (short)hu; vm[j] = (short)mu;
        }
        ah[t] = vh; am[t] = vm;
    }
    // full row norm: lane and lane^32 share a row, complementary k-halves
    xxl += __shfl_xor(xxl, 32, 64);
    if (lane < 32) xx_s[rloc] = xxl;
    __syncthreads();

    float xxr[16];
    #pragma unroll
    for (int r = 0; r < 16; ++r)
        xxr[r] = xx_s[(w << 5) + (r & 3) + ((r >> 2) << 3) + hi4];

    unsigned int best[16];
    #pragma unroll
    for (int r = 0; r < 16; ++r) best[r] = 0xFFFFFFFFu;

    const int col = lane & 31;
    const int rowbase = bid * 128 + (w << 5);

    // ---- main loop: 16 col-tiles of 32 codes; 3-term split MFMA; no barriers
    for (int c = 0; c < 16; ++c) {
        f32x16 acc0 = {};
        f32x16 acc1 = {};
        const bf16x8* ph = (const bf16x8*)cbh + c * 512 + lane;
        const bf16x8* pm = (const bf16x8*)cbm + c * 512 + lane;
        #pragma unroll
        for (int t = 0; t < 8; ++t) {
            bf16x8 bh = ph[t * 64];
            bf16x8 bm = pm[t * 64];
            acc0 = __builtin_amdgcn_mfma_f32_32x32x16_bf16(ah[t], bh, acc0, 0, 0, 0);
            acc1 = __builtin_amdgcn_mfma_f32_32x32x16_bf16(ah[t], bm, acc1, 0, 0, 0);
            acc0 = __builtin_amdgcn_mfma_f32_32x32x16_bf16(am[t], bh, acc0, 0, 0, 0);
        }
        const int kcol = (c << 5) + col;
        const float wwc = ww[kcol];
        #pragma unroll
        for (int r = 0; r < 16; ++r) {
            float dot  = acc0[r] + acc1[r];
            float dist = fmaf(-2.f, dot, xxr[r] + wwc);
            int rl = (r & 3) + ((r >> 2) << 3) + hi4;
            __builtin_nontemporal_store(dist,
                &out[(size_t)D_OFF + (size_t)(rowbase + rl) * NK + kcol]);
            unsigned int pack = (f2u(dist) & ~511u) | (unsigned int)kcol;
            best[r] = pack < best[r] ? pack : best[r];
        }
    }

    // ---- argmin: u32 shuffle-min over the 32-lane column group
    #pragma unroll
    for (int r = 0; r < 16; ++r) {
        unsigned int b = best[r];
        #pragma unroll
        for (int m = 16; m >= 1; m >>= 1) {
            unsigned int ob = __shfl_xor(b, m, 64);
            b = ob < b ? ob : b;
        }
        best[r] = b;
    }
    if ((lane & 31) == 0) {
        #pragma unroll
        for (int r = 0; r < 16; ++r) {
            int row = (w << 5) + (r & 3) + ((r >> 2) << 3) + hi4;
            idx_s[row] = (int)(best[r] & 511u);
            red_s[row] = u2f(best[r] & ~511u);
        }
    }
    __syncthreads();

    // ---- loss partial (wave 0) — deterministic shuffle sum
    if (tid < 64) {
        float s = red_s[tid] + red_s[tid + 64];
        #pragma unroll
        for (int m = 32; m >= 1; m >>= 1) s += __shfl_xor(s, m, 64);
        if (tid == 0) partials[bid] = s;
    }

    // ---- quantized: page-dense stores — each wave inst = 2 x 512B contiguous
    // lane = spatial quad (4 consecutive spatial), 4 scalar L2-hot cb gathers
    {
        int l31 = tid & 31;            // spatial quad 0..31 -> spatial 4*l31..+3
        int dhi = tid >> 5;            // 0..7: d = it*8 + dhi
        const float* c0 = cb + (size_t)idx_s[4 * l31    ] * DIM;
        const float* c1 = cb + (size_t)idx_s[4 * l31 + 1] * DIM;
        const float* c2 = cb + (size_t)idx_s[4 * l31 + 2] * DIM;
        const float* c3 = cb + (size_t)idx_s[4 * l31 + 3] * DIM;
        float* ob = out + (size_t)bb * (DIM * SPB) + s0 + (l31 << 2);
        #pragma unroll
        for (int it = 0; it < 16; ++it) {
            int d = (it << 3) + dhi;
            f32x4 v;
            v[0] = c0[d]; v[1] = c1[d]; v[2] = c2[d]; v[3] = c3[d];
            __builtin_nontemporal_store(v, (f32x4*)(ob + (size_t)d * SPB));
        }
    }

    // ---- encoding one-hot: fused zero+one-hot, lane-contiguous f32x4 nt stores
    {
        float* ebase = out + (size_t)E_OFF + (size_t)bid * (128 * NK);
        #pragma unroll
        for (int j = 0; j < 64; ++j) {
            int v   = j * 256 + tid;       // f32x4 index within block's 128x512 region
            int r   = v >> 7;
            int cb4 = (v & 127) << 2;
            int idxr = idx_s[r];
            f32x4 val;
            val[0] = (idxr == cb4    ) ? 1.0f : 0.0f;
            val[1] = (idxr == cb4 + 1) ? 1.0f : 0.0f;
            val[2] = (idxr == cb4 + 2) ? 1.0f : 0.0f;
            val[3] = (idxr == cb4 + 3) ? 1.0f : 0.0f;
            __builtin_nontemporal_store(val, (f32x4*)ebase + v);
        }
    }
}

__global__ __launch_bounds__(256) void loss_kernel(const float* __restrict__ partials,
                                                   float* __restrict__ out) {
    __shared__ double sd[256];
    int tid = threadIdx.x;
    double s = 0.0;
    for (int i = tid; i < NBLK; i += 256) s += (double)partials[i];
    sd[tid] = s;
    __syncthreads();
    for (int k = 128; k > 0; k >>= 1) {
        if (tid < k) sd[tid] += sd[tid + k];
        __syncthreads();
    }
    if (tid == 0) out[L_OFF] = (float)(2.0 * sd[0] / 16777216.0);
}

extern "C" void kernel_launch(void* const* d_in, const int* in_sizes, int n_in,
                              void* d_out, int out_size, void* d_ws, size_t ws_size,
                              hipStream_t stream) {
    const float* x  = (const float*)d_in[0];
    const float* cb = (const float*)d_in[1];
    float* out = (float*)d_out;
    char*  ws  = (char*)d_ws;
    float* ww  = (float*)ws;                          // 2048 B
    short* cbh = (short*)(ws + 2048);                 // 131072 B
    short* cbm = (short*)(ws + 2048 + 131072);        // 131072 B
    float* partials = (float*)(ws + 2048 + 262144);   // 4096 B

    prep_kernel<<<32, 256, 0, stream>>>(cb, ww, cbh, cbm);
    vq_main<<<NBLK, 256, 0, stream>>>(x, cb, ww, cbh, cbm, out, partials);
    loss_kernel<<<1, 256, 0, stream>>>(partials, out);
}

// Round 10
// 132.134 us; speedup vs baseline: 1.6005x; 1.3432x over previous
//
#include <hip/hip_runtime.h>
#include <stdint.h>

#define DIM   128
#define NK    512
#define SPB   32768
#define NBLK  1024

#define E_OFF 16777216
#define D_OFF 83886080
#define L_OFF 150994944

typedef __attribute__((ext_vector_type(16))) float f32x16;
typedef __attribute__((ext_vector_type(4)))  float f32x4;
typedef __attribute__((ext_vector_type(8)))  short bf16x8;

__device__ __forceinline__ unsigned int rne_bf16(float f) {
    union { float f; unsigned int u; } v; v.f = f;
    return (v.u + 0x7FFFu + ((v.u >> 16) & 1u)) >> 16;
}
__device__ __forceinline__ float bf16f(unsigned int h) {
    union { float f; unsigned int u; } v; v.u = h << 16;
    return v.f;
}
__device__ __forceinline__ unsigned int f2u(float f) {
    union { float f; unsigned int u; } v; v.f = f; return v.u;
}
__device__ __forceinline__ float u2f(unsigned int u) {
    union { float f; unsigned int u; } v; v.u = u; return v.f;
}

// Pre-kernel: codebook bf16-rounded + sq-norms OF THE ROUNDED rows (so dist =
// exact distance between rounded vectors + code-independent offset -> minimal
// argmin perturbation for bf16 storage). Fragment-major layout:
// index ((c*8+t)*64 + lane), 8 bf16/lane = cb[c*32+(l&31)][t*16+(l>>5)*8+j]
__global__ __launch_bounds__(256) void prep_kernel(
        const float* __restrict__ cb, float* __restrict__ ww,
        short* __restrict__ cbh) {
    const int tid = blockIdx.x * 256 + threadIdx.x;   // 0..8191
    if (tid < NK) {
        const float* row = cb + tid * DIM;
        float s = 0.f;
        #pragma unroll 8
        for (int d = 0; d < DIM; ++d) {
            float r = bf16f(rne_bf16(row[d]));
            s = fmaf(r, r, s);
        }
        ww[tid] = s;
    }
    const int l = tid & 63;
    const int t = (tid >> 6) & 7;
    const int c = tid >> 9;
    const float* src = cb + (c * 32 + (l & 31)) * DIM + t * 16 + ((l >> 5) << 3);
    bf16x8 vh;
    #pragma unroll
    for (int j = 0; j < 8; ++j) vh[j] = (short)rne_bf16(src[j]);
    ((bf16x8*)cbh)[tid] = vh;
}

__global__ __launch_bounds__(256, 4) void vq_main(
        const float* __restrict__ x, const float* __restrict__ cb,
        const float* __restrict__ ww,
        const short* __restrict__ cbh,
        float* __restrict__ out, float* __restrict__ partials) {
    __shared__ float xx_s[128];
    __shared__ int   idx_s[128];
    __shared__ float red_s[128];

    const int tid  = threadIdx.x;
    const int bid  = blockIdx.x;
    const int lane = tid & 63;
    const int w    = tid >> 6;
    const int bb   = bid >> 8;            // batch index (256 blocks per batch elem)
    const int s0   = (bid & 255) << 7;    // spatial base
    const int hi4  = (lane >> 5) << 2;
    const int rloc = (w << 5) + (lane & 31);   // this lane's x row (0..127)
    const int kb   = (lane >> 5) << 3;         // k-offset 0 or 8

    const float* xrow = x + (size_t)bb * (DIM * SPB) + s0 + rloc;

    // ---- phase 1: direct global fragment loads (nt) + bf16 round + true norm
    bf16x8 ah[8];
    float xxl = 0.f;
    #pragma unroll
    for (int t = 0; t < 8; ++t) {
        bf16x8 vh;
        #pragma unroll
        for (int j = 0; j < 8; ++j) {
            float f = __builtin_nontemporal_load(xrow + (size_t)(t * 16 + kb + j) * SPB);
            xxl = fmaf(f, f, xxl);
            vh[j] = (short)rne_bf16(f);
        }
        ah[t] = vh;
    }
    // full row norm: lane and lane^32 share a row, complementary k-halves
    xxl += __shfl_xor(xxl, 32, 64);
    if (lane < 32) xx_s[rloc] = xxl;
    __syncthreads();

    float xxr[16];
    #pragma unroll
    for (int r = 0; r < 16; ++r)
        xxr[r] = xx_s[(w << 5) + (r & 3) + ((r >> 2) << 3) + hi4];

    unsigned int best[16];
    #pragma unroll
    for (int r = 0; r < 16; ++r) best[r] = 0xFFFFFFFFu;

    const int col = lane & 31;
    const int rowbase = bid * 128 + (w << 5);

    // ---- main loop: 16 col-tiles of 32 codes; single-term bf16 MFMA; no barriers
    for (int c = 0; c < 16; ++c) {
        f32x16 acc = {};
        const bf16x8* ph = (const bf16x8*)cbh + c * 512 + lane;
        #pragma unroll
        for (int t = 0; t < 8; ++t) {
            bf16x8 bh = ph[t * 64];
            acc = __builtin_amdgcn_mfma_f32_32x32x16_bf16(ah[t], bh, acc, 0, 0, 0);
        }
        const int kcol = (c << 5) + col;
        const float wwc = ww[kcol];
        #pragma unroll
        for (int r = 0; r < 16; ++r) {
            float dist = fmaf(-2.f, acc[r], xxr[r] + wwc);
            int rl = (r & 3) + ((r >> 2) << 3) + hi4;
            __builtin_nontemporal_store(dist,
                &out[(size_t)D_OFF + (size_t)(rowbase + rl) * NK + kcol]);
            unsigned int pack = (f2u(dist) & ~511u) | (unsigned int)kcol;
            best[r] = pack < best[r] ? pack : best[r];
        }
    }

    // ---- argmin: u32 shuffle-min over the 32-lane column group
    #pragma unroll
    for (int r = 0; r < 16; ++r) {
        unsigned int b = best[r];
        #pragma unroll
        for (int m = 16; m >= 1; m >>= 1) {
            unsigned int ob = __shfl_xor(b, m, 64);
            b = ob < b ? ob : b;
        }
        best[r] = b;
    }
    if ((lane & 31) == 0) {
        #pragma unroll
        for (int r = 0; r < 16; ++r) {
            int row = (w << 5) + (r & 3) + ((r >> 2) << 3) + hi4;
            idx_s[row] = (int)(best[r] & 511u);
            red_s[row] = u2f(best[r] & ~511u);
        }
    }
    __syncthreads();

    // ---- loss partial (wave 0) — deterministic shuffle sum
    if (tid < 64) {
        float s = red_s[tid] + red_s[tid + 64];
        #pragma unroll
        for (int m = 32; m >= 1; m >>= 1) s += __shfl_xor(s, m, 64);
        if (tid == 0) partials[bid] = s;
    }

    // ---- quantized: gather cb row to regs, scalar column stores (2x128B/inst)
    {
        int r = tid >> 1, h = tid & 1;
        const float* src = cb + (size_t)idx_s[r] * DIM + h * 64;
        float* ob = out + (size_t)bb * (DIM * SPB) + s0 + r;
        #pragma unroll
        for (int q = 0; q < 16; ++q) {
            f32x4 v = *(const f32x4*)(src + (q << 2));
            #pragma unroll
            for (int e = 0; e < 4; ++e) {
                int d = h * 64 + (q << 2) + e;
                __builtin_nontemporal_store(v[e], &ob[(size_t)d * SPB]);
            }
        }
    }

    // ---- encoding one-hot: fused zero+one-hot, lane-contiguous f32x4 nt stores
    {
        float* ebase = out + (size_t)E_OFF + (size_t)bid * (128 * NK);
        #pragma unroll
        for (int j = 0; j < 64; ++j) {
            int v   = j * 256 + tid;       // f32x4 index within block's 128x512 region
            int r   = v >> 7;
            int cb4 = (v & 127) << 2;
            int idxr = idx_s[r];
            f32x4 val;
            val[0] = (idxr == cb4    ) ? 1.0f : 0.0f;
            val[1] = (idxr == cb4 + 1) ? 1.0f : 0.0f;
            val[2] = (idxr == cb4 + 2) ? 1.0f : 0.0f;
            val[3] = (idxr == cb4 + 3) ? 1.0f : 0.0f;
            __builtin_nontemporal_store(val, (f32x4*)ebase + v);
        }
    }
}

__global__ __launch_bounds__(256) void loss_kernel(const float* __restrict__ partials,
                                                   float* __restrict__ out) {
    __shared__ double sd[256];
    int tid = threadIdx.x;
    double s = 0.0;
    for (int i = tid; i < NBLK; i += 256) s += (double)partials[i];
    sd[tid] = s;
    __syncthreads();
    for (int k = 128; k > 0; k >>= 1) {
        if (tid < k) sd[tid] += sd[tid + k];
        __syncthreads();
    }
    if (tid == 0) out[L_OFF] = (float)(2.0 * sd[0] / 16777216.0);
}

extern "C" void kernel_launch(void* const* d_in, const int* in_sizes, int n_in,
                              void* d_out, int out_size, void* d_ws, size_t ws_size,
                              hipStream_t stream) {
    const float* x  = (const float*)d_in[0];
    const float* cb = (const float*)d_in[1];
    float* out = (float*)d_out;
    char*  ws  = (char*)d_ws;
    float* ww  = (float*)ws;                          // 2048 B
    short* cbh = (short*)(ws + 2048);                 // 131072 B
    float* partials = (float*)(ws + 2048 + 131072);   // 4096 B

    prep_kernel<<<32, 256, 0, stream>>>(cb, ww, cbh);
    vq_main<<<NBLK, 256, 0, stream>>>(x, cb, ww, cbh, out, partials);
    loss_kernel<<<1, 256, 0, stream>>>(partials, out);
}